// Round 18
// baseline (65.980 us; speedup 1.0000x reference)
//
#include <hip/hip_runtime.h>
#include <hip/hip_bf16.h>

typedef float f32x4 __attribute__((ext_vector_type(4)));
typedef int   i32x4 __attribute__((ext_vector_type(4)));
typedef int   i32x8 __attribute__((ext_vector_type(8)));

#define NC 4096
#define ND 1024
#define NVP 256     // padded compact-row count (B*A = 256 annotations max)
#define EPSF 1e-10f
#define SCALE1 127  // E8M0 exponent byte for 2^0
#define NBLK 256

// Fragment layout (rounds 8-17 verified): frag = 2048 B;
//   byte = half*1024 + (hi*16+lo)*16 + b  with  row = R16*16+lo,
//   k-in-tile = hi*32 + half*16 + b.  LDFRAG reads lane*16 and +1024.

// ---------------- K0: zero accum/ticket (ws poisoned 0xAA before timing) ----------------
__global__ void zero_kernel(float* __restrict__ accum, int* __restrict__ ticket) {
  int t = threadIdx.x;
  if (t < 8) accum[t] = 0.f;
  if (t == 8) *ticket = 0;
}

// ---------------- K1: fully block-independent fused pipeline ----------------
// Block bj: bitmap+compact (LDS) -> P rows [bj*16,+16) -> bfrag ->
// per kt: self-convert ALL compact F rows' k-slice into LDS A-slab -> MFMA.
// No cross-block dataflow except the final fence-free atomic+ticket (R17-proven).
#define LDFRAG(V, BASEPTR, FID)                                               \
  do {                                                                        \
    const unsigned char* _p = (BASEPTR) + (size_t)(FID) * 2048 + lane * 16;   \
    i32x4 _l0 = *(const i32x4*)(_p);                                          \
    i32x4 _l1 = *(const i32x4*)(_p + 1024);                                   \
    V = __builtin_shufflevector(_l0, _l1, 0, 1, 2, 3, 4, 5, 6, 7);            \
  } while (0)

__global__ __launch_bounds__(512)
void fused_kernel(const int* __restrict__ ann, int n_ann,
                  const float* __restrict__ F, const float* __restrict__ P,
                  float* __restrict__ accum, int* __restrict__ ticket,
                  float* __restrict__ out) {
  __shared__ unsigned char mark[NC];
  __shared__ int vloc[NVP];
  __shared__ int wsum[8];
  __shared__ __attribute__((aligned(16))) unsigned char bfrag[8 * 2048];   // P frags
  __shared__ __attribute__((aligned(16))) unsigned char afrag[16 * 2048];  // F slab (per kt)
  __shared__ float f2loc[NVP];
  __shared__ float p2l[16], psl[16], redI[8], redE[8], redN[8];
  const int tid = threadIdx.x;
  const int lane = tid & 63, wid = tid >> 6;
  const int bj = blockIdx.x;  // 16 P rows per block

  // ---- 1. bitmap + deterministic compact (ascending class id) ----
  for (int i = tid; i < NC; i += 512) mark[i] = 0;
  __syncthreads();
  for (int t = tid; t < n_ann; t += 512) {
    int idx = ann[t * 5 + 4];
    if (idx >= 0 && idx < NC) mark[idx] = 1;  // benign race: all write 1
  }
  __syncthreads();
  int lc = 0;
  {
    int base = tid * 8;
    #pragma unroll
    for (int k = 0; k < 8; ++k) lc += mark[base + k];
  }
  int inc = lc;
  #pragma unroll
  for (int off = 1; off < 64; off <<= 1) {
    int v = __shfl_up(inc, off);
    if (lane >= off) inc += v;
  }
  if (lane == 63) wsum[wid] = inc;
  __syncthreads();
  int wbase = 0;
  for (int w = 0; w < wid; ++w) wbase += wsum[w];
  int pos = wbase + inc - lc;  // exclusive prefix
  {
    int base = tid * 8;
    for (int k = 0; k < 8; ++k)
      if (mark[base + k]) vloc[pos++] = base + k;
  }
  const int total = wsum[0] + wsum[1] + wsum[2] + wsum[3] +
                    wsum[4] + wsum[5] + wsum[6] + wsum[7];
  __syncthreads();
  for (int i = total + tid; i < NVP; i += 512) vloc[i] = 0;  // padded -> row 0
  __syncthreads();

  // ---- 2. P-convert 16 rows -> swizzled bfrag + norms (R17-proven) ----
  {
    const int r = tid >> 5;    // row 0..15
    const int seg = tid & 31;  // float4 lane within row
    const float* src = P + (size_t)(bj * 16 + r) * ND;
    float sq = 0.f, sm = 0.f;
    #pragma unroll
    for (int i = 0; i < 8; ++i) {
      float4 v = *reinterpret_cast<const float4*>(src + (seg + i * 32) * 4);
      int pk = __builtin_amdgcn_cvt_pk_fp8_f32(v.x, v.y, 0, false);
      pk = __builtin_amdgcn_cvt_pk_fp8_f32(v.z, v.w, pk, true);
      int addr = i * 2048 + r * 128 + ((seg * 4) ^ ((r & 7) << 4));
      *reinterpret_cast<int*>(&bfrag[addr]) = pk;
      sq += v.x * v.x + v.y * v.y + v.z * v.z + v.w * v.w;
      sm += v.x + v.y + v.z + v.w;
    }
    #pragma unroll
    for (int off = 16; off; off >>= 1) {
      sq += __shfl_down(sq, off, 32);
      sm += __shfl_down(sm, off, 32);
    }
    if ((tid & 31) == 0) { p2l[r] = sq; psl[r] = sm; }
  }

  // ---- 3. K-loop: self-convert F slab (per kt) + MFMA ----
  const int lo = lane & 15, hi = lane >> 4;
  const int ci = tid >> 1;        // compact slot this thread converts
  const int hk = tid & 1;         // which 64-elem half of the 128-k window
  const int prow = vloc[ci];
  const float* fbase = F + (size_t)prow * ND + hk * 64;
  unsigned char* adst = &afrag[(ci >> 4) * 2048 + (ci & 15) * 16];
  f32x4 acc0 = {0.f, 0.f, 0.f, 0.f}, acc1 = acc0;
  const int fbA = wid * 2;        // wave w owns compact rows [w*32, w*32+32)
  #pragma unroll 1
  for (int kt = 0; kt < 8; ++kt) {
    __syncthreads();  // afrag of previous kt fully consumed; bfrag stable
    {
      float sq = 0.f;
      const float* fsrc = fbase + kt * 128;
      #pragma unroll
      for (int j = 0; j < 16; ++j) {
        float4 v = *reinterpret_cast<const float4*>(fsrc + j * 4);
        int pk = __builtin_amdgcn_cvt_pk_fp8_f32(v.x, v.y, 0, false);
        pk = __builtin_amdgcn_cvt_pk_fp8_f32(v.z, v.w, pk, true);
        int kh = hk * 64 + j * 4;
        *reinterpret_cast<int*>(adst + ((kh >> 4) & 1) * 1024 +
                                (kh >> 5) * 256 + (kh & 15)) = pk;
        sq += v.x * v.x + v.y * v.y + v.z * v.z + v.w * v.w;
      }
      sq += __shfl_xor(sq, 1);   // combine the two halves of this row
      if (hk == 0) f2loc[ci] = (kt == 0) ? sq : (f2loc[ci] + sq);
    }
    __syncthreads();  // afrag (and f2loc) ready
    i32x8 a0, a1, b;
    LDFRAG(a0, afrag, fbA);
    LDFRAG(a1, afrag, fbA + 1);
    {
      int x = (lo & 7) << 4;
      const unsigned char* bb = &bfrag[kt * 2048 + lo * 128];
      i32x4 l0 = *reinterpret_cast<const i32x4*>(bb + ((hi * 32) ^ x));
      i32x4 l1 = *reinterpret_cast<const i32x4*>(bb + ((hi * 32 + 16) ^ x));
      b = __builtin_shufflevector(l0, l1, 0, 1, 2, 3, 4, 5, 6, 7);
    }
    acc0 = __builtin_amdgcn_mfma_scale_f32_16x16x128_f8f6f4(
        a0, b, acc0, 0, 0, 0, SCALE1, 0, SCALE1);
    acc1 = __builtin_amdgcn_mfma_scale_f32_16x16x128_f8f6f4(
        a1, b, acc1, 0, 0, 0, SCALE1, 0, SCALE1);
  }

  // ---- Epilogue. C/D: col = lane&15 (P row), row = (lane>>4)*4+reg (F row) ----
  float intra_l = 0.f, inter_l = 0.f;
  {
    const int gj = bj * 16 + lo;
    const float p2j = p2l[lo];
    const bool mj = psl[lo] != 0.f;
    if (mj) {
      #pragma unroll
      for (int f = 0; f < 2; ++f) {
        f32x4 a = f ? acc1 : acc0;
        #pragma unroll
        for (int r = 0; r < 4; ++r) {
          int cc = wid * 32 + f * 16 + hi * 4 + r;
          if (cc < total) {
            float msd = fmaxf(f2loc[cc] + p2j - 2.f * a[r], 0.f) * (1.f / 1024.f);
            int gi = vloc[cc];
            if (gi == gj) {
              intra_l += msd;                 // diagonal: intra
            } else if (msd < 1.0f) {          // inter nonzero only if s<1
              float s = sqrtf(fmaxf(msd, 1e-12f));
              float e = 1.f - s;
              float e2 = e * e;
              inter_l += e2 * e2;             // (e/M)^2 * max(e,0)^2, M=1
            }
          }
        }
      }
    }
  }
  float ndl = 0.f;
  for (int c = tid; c < total; c += 512) {
    int v = vloc[c];
    if ((v >> 4) == bj && psl[v & 15] != 0.f) ndl += 1.f;
  }
  #pragma unroll
  for (int off = 32; off; off >>= 1) {
    intra_l += __shfl_down(intra_l, off);
    inter_l += __shfl_down(inter_l, off);
    ndl     += __shfl_down(ndl, off);
  }
  if (lane == 0) { redI[wid] = intra_l; redE[wid] = inter_l; redN[wid] = ndl; }
  __syncthreads();

  if (tid == 0) {
    float si = 0.f, se = 0.f, nd = 0.f;
    #pragma unroll
    for (int w = 0; w < 8; ++w) { si += redI[w]; se += redE[w]; nd += redN[w]; }
    float nj = 0.f;
    #pragma unroll
    for (int r = 0; r < 16; ++r) nj += (psl[r] != 0.f) ? 1.f : 0.f;
    // Fence-free completion protocol (R17-proven): device-scope atomics hit
    // the global coherence point; wave-local vmcnt(0) orders the ticket.
    atomicAdd(&accum[0], si);
    atomicAdd(&accum[1], se);
    atomicAdd(&accum[2], nj);  // exact: integer-valued
    atomicAdd(&accum[3], nd);
    asm volatile("s_waitcnt vmcnt(0)" ::: "memory");
    int tkt = atomicAdd(ticket, 1);
    if (tkt == NBLK - 1) {     // last block: all prior atomics completed
      float a0 = atomicAdd(&accum[0], 0.f);
      float a1 = atomicAdd(&accum[1], 0.f);
      float fnj = atomicAdd(&accum[2], 0.f);
      float fnd = atomicAdd(&accum[3], 0.f);
      float fni = (float)total;
      out[0] = a0 / (fnd + EPSF);
      out[1] = a1 / (fni * fnj - fnd + EPSF);
    }
  }
}

extern "C" void kernel_launch(void* const* d_in, const int* in_sizes, int n_in,
                              void* d_out, int out_size, void* d_ws, size_t ws_size,
                              hipStream_t stream) {
  const float* F = (const float*)d_in[0];
  const float* P = (const float*)d_in[1];
  const int* ann = (const int*)d_in[2];
  int n_ann = in_sizes[2] / 5;

  char* ws = (char*)d_ws;
  float* accum  = (float*)ws;        // 8 f32
  int*   ticket = (int*)(accum + 8); // 1 i32

  float* out = (float*)d_out;

  zero_kernel<<<1, 64, 0, stream>>>(accum, ticket);
  fused_kernel<<<NBLK, 512, 0, stream>>>(ann, n_ann, F, P, accum, ticket, out);
}